// Round 7
// baseline (247.062 us; speedup 1.0000x reference)
//
#include <hip/hip_runtime.h>
#include <hip/hip_bf16.h>

#define NB 128
#define NT 4096
#define ND 64
#define CH 128            // t-rows per block
#define NCHUNK 32         // NT / CH

typedef __attribute__((ext_vector_type(8))) short bf16x8;
typedef __attribute__((ext_vector_type(4))) float f32x4;

__device__ __forceinline__ short bfb(float f) {
    __hip_bfloat16 h = __float2bfloat16(f);
    return __builtin_bit_cast(short, h);
}

__device__ __forceinline__ bf16x8 pack8(f32x4 a, f32x4 b) {
    bf16x8 r;
    r[0] = bfb(a[0]); r[1] = bfb(a[1]); r[2] = bfb(a[2]); r[3] = bfb(a[3]);
    r[4] = bfb(b[0]); r[5] = bfb(b[1]); r[6] = bfb(b[2]); r[7] = bfb(b[3]);
    return r;
}

// ws layout (bytes)
#define OFF_SPART 0                    // float[128][32][64]  = 1 MB
#define OFF_WB    (1048576)            // bf16x8[1536]        = 24 KB
#define OFF_W2T   (OFF_WB + 32768)     // float[64][64]       = 16 KB
#define OFF_WL1T  (OFF_W2T + 16384)    // float[64][256]      = 64 KB
#define OFF_WL2T  (OFF_WL1T + 65536)   // float[256][256]     = 256 KB
#define OFF_WL3T  (OFF_WL2T + 262144)  // float[256][512]     = 512 KB

#define N_WB   1536
#define N_W2T  4096
#define N_WL1T 16384
#define N_WL2T 65536
#define N_WL3T 131072
#define PREP_TOTAL (N_WB + N_W2T + N_WL1T + N_WL2T + N_WL3T)   // 218624

// ---------------------------------------------------------------------------
// Prep: bf16 W1 MFMA fragments + transposed MLP weights ([k][o] layouts).
// ---------------------------------------------------------------------------
__global__ __launch_bounds__(256) void prep_kernel(
    const float* __restrict__ W1, const float* __restrict__ W2,
    const float* __restrict__ Wl1, const float* __restrict__ Wl2,
    const float* __restrict__ Wl3,
    short* __restrict__ wb, float* __restrict__ W2T, float* __restrict__ Wl1T,
    float* __restrict__ Wl2T, float* __restrict__ Wl3T)
{
    int idx = blockIdx.x * 256 + threadIdx.x;
    if (idx < N_WB) {
        int lane = idx & 63;
        int kk   = (idx >> 6) % 6;
        int nt   = idx / (6 * 64);
        const float* wp = W1 + (nt * 16 + (lane & 15)) * 192 + (lane >> 4) * 8 + kk * 32;
        bf16x8 r;
        #pragma unroll
        for (int j = 0; j < 8; ++j) r[j] = bfb(wp[j]);
        reinterpret_cast<bf16x8*>(wb)[idx] = r;
        return;
    }
    idx -= N_WB;
    if (idx < N_W2T)  { W2T[idx]  = W2[(idx & 63) * 64 + (idx >> 6)]; return; }
    idx -= N_W2T;
    if (idx < N_WL1T) { Wl1T[idx] = Wl1[(idx & 255) * 64 + (idx >> 8)]; return; }
    idx -= N_WL1T;
    if (idx < N_WL2T) { Wl2T[idx] = Wl2[(idx & 255) * 256 + (idx >> 8)]; return; }
    idx -= N_WL2T;
    if (idx < N_WL3T) { Wl3T[idx] = Wl3[(idx & 511) * 256 + (idx >> 9)]; return; }
}

// ---------------------------------------------------------------------------
// Conv(k=3) + ReLU + masked sum -> s_part[b][chunk][64] (non-atomic).
// 4096 blocks x 256 threads (4 waves). Wave w handles tiles 2w, 2w+1
// (rows tbase..tbase+33) and stages its own 36 rows into a private LDS
// region via global_load_lds (unit-XOR swizzle), decoupled by a per-wave
// s_waitcnt vmcnt(0) -- no block barrier on the staging path.
// ---------------------------------------------------------------------------
__global__ __launch_bounds__(256) void conv_pool_kernel(
    const float* __restrict__ x, const int* __restrict__ lengths,
    const short* __restrict__ wb, const float* __restrict__ b1,
    float* __restrict__ s_part)
{
    __shared__ float lds[4 * 36 * 64];   // 36 KB: 4 waves x 36 rows x 64 f
    __shared__ float sh_red[256];

    const int b      = blockIdx.x >> 5;
    const int chunk  = blockIdx.x & (NCHUNK - 1);
    const int nvalid = lengths[b] - 2;
    const int t0     = chunk * CH;
    float* slot = s_part + ((size_t)b * NCHUNK + chunk) * 64;
    if (t0 >= nvalid) {                  // dead chunk: zero the slot (poison!)
        if (threadIdx.x < 64) slot[threadIdx.x] = 0.f;
        return;
    }

    const int lane = threadIdx.x & 63;
    const int wave = threadIdx.x >> 6;
    const int lrow = lane & 15;
    const int lkg  = lane >> 4;

    const float* xb = x + (size_t)b * (NT * ND);
    const int tbase = t0 + wave * 32;
    const bool t0v = tbase < nvalid;
    const bool t1v = (tbase + 16) < nvalid;
    float* ldsw = &lds[wave * (36 * 64)];

    if (t0v) {       // stage rows tbase .. tbase+35 (clamped) into ldsw
        const int nsegs = t1v ? 9 : 5;
        const int jl   = lane >> 4;      // 0..3
        const int unit = lane & 15;
        for (int s = 0; s < nsegs; ++s) {
            const int j  = s * 4 + jl;
            int rg = tbase + j; if (rg > NT - 1) rg = NT - 1;
            const int su = unit ^ (j & 7);
            const float* src = xb + (size_t)rg * ND + su * 4;
            __builtin_amdgcn_global_load_lds(
                (const __attribute__((address_space(1))) void*)src,
                (__attribute__((address_space(3))) void*)&ldsw[s * 256],
                16, 0, 0);
        }
    }

    float b1f[4];
    #pragma unroll
    for (int nt = 0; nt < 4; ++nt) b1f[nt] = b1[nt * 16 + lrow];

    asm volatile("s_waitcnt vmcnt(0)" ::: "memory");   // per-wave drain

    const bf16x8* wb8 = reinterpret_cast<const bf16x8*>(wb);
    float sums[4] = {0.f, 0.f, 0.f, 0.f};

    #pragma unroll
    for (int i = 0; i < 2; ++i) {
        if (i == 0 ? t0v : t1v) {
            f32x4 acc[4];
            #pragma unroll
            for (int nt = 0; nt < 4; ++nt) acc[nt] = (f32x4){0.f, 0.f, 0.f, 0.f};

            #pragma unroll
            for (int kk = 0; kk < 6; ++kk) {
                const int j  = i * 16 + lrow + (kk >> 1);
                const int e  = lkg * 2 + (kk & 1) * 8;
                const int sw = j & 7;
                f32x4 a0 = *reinterpret_cast<const f32x4*>(&ldsw[j * 64 + ((e ^ sw) << 2)]);
                f32x4 a1 = *reinterpret_cast<const f32x4*>(&ldsw[j * 64 + (((e + 1) ^ sw) << 2)]);
                bf16x8 af = pack8(a0, a1);
                #pragma unroll
                for (int nt = 0; nt < 4; ++nt)
                    acc[nt] = __builtin_amdgcn_mfma_f32_16x16x32_bf16(
                        af, wb8[(nt * 6 + kk) * 64 + lane], acc[nt], 0, 0, 0);
            }

            // C layout: col(f)=lane&15, row(t)=(lane>>4)*4+r  [m89/m91]
            #pragma unroll
            for (int r = 0; r < 4; ++r) {
                const bool valid = (tbase + i * 16 + lkg * 4 + r) < nvalid;
                #pragma unroll
                for (int nt = 0; nt < 4; ++nt) {
                    float v = fmaxf(acc[nt][r] + b1f[nt], 0.f);
                    if (valid) sums[nt] += v;
                }
            }
        }
    }

    #pragma unroll
    for (int nt = 0; nt < 4; ++nt) {
        float v = sums[nt];
        v += __shfl_xor(v, 16, 64);
        v += __shfl_xor(v, 32, 64);
        if (lane < 16) sh_red[wave * 64 + nt * 16 + lane] = v;
    }
    __syncthreads();
    if (threadIdx.x < 64)
        slot[threadIdx.x] = sh_red[threadIdx.x] + sh_red[64 + threadIdx.x] +
                            sh_red[128 + threadIdx.x] + sh_red[192 + threadIdx.x];
}

// ---------------------------------------------------------------------------
// Per-b: reduce chunk partials -> mean, pointwise W2+b2, 3-layer MLP.
// All weight loads lane-coalesced via transposed [k][o] layouts.
// ---------------------------------------------------------------------------
__global__ __launch_bounds__(256) void mlp_kernel(
    const float* __restrict__ s_part, const int* __restrict__ lengths,
    const float* __restrict__ W2T, const float* __restrict__ b2,
    const float* __restrict__ Wl1T, const float* __restrict__ bl1,
    const float* __restrict__ Wl2T, const float* __restrict__ bl2,
    const float* __restrict__ Wl3T, const float* __restrict__ bl3,
    float* __restrict__ out)
{
    __shared__ float sh_r[256], sh_s[64], sh_p[64], sh_z1[256], sh_z2[256];
    const int b = blockIdx.x, tid = threadIdx.x;

    {   // reduce 32 chunk partials; threads split 4-way over chunks
        const int f = tid & 63, c0 = tid >> 6;
        const float* sp = s_part + (size_t)b * NCHUNK * 64;
        float p = 0.f;
        #pragma unroll
        for (int c = 0; c < 8; ++c) p += sp[(c0 + c * 4) * 64 + f];
        sh_r[tid] = p;
    }
    __syncthreads();
    if (tid < 64)
        sh_s[tid] = (sh_r[tid] + sh_r[64 + tid] + sh_r[128 + tid] + sh_r[192 + tid])
                    / (float)(lengths[b] - 2);
    __syncthreads();

    if (tid < 64) {   // pooled[g] = sum_f mean[f]*W2T[f][g] + b2[g]
        float acc = b2[tid];
        #pragma unroll 8
        for (int f = 0; f < 64; ++f) acc = fmaf(W2T[f * 64 + tid], sh_s[f], acc);
        sh_p[tid] = acc;
    }
    __syncthreads();

    {   // z1[o] = relu(sum_f pooled[f]*Wl1T[f][o] + bl1[o])
        float acc = bl1[tid];
        #pragma unroll 8
        for (int f = 0; f < 64; ++f) acc = fmaf(Wl1T[f * 256 + tid], sh_p[f], acc);
        sh_z1[tid] = fmaxf(acc, 0.f);
    }
    __syncthreads();

    {   // z2[o] = relu(sum_k z1[k]*Wl2T[k][o] + bl2[o])
        float acc = bl2[tid];
        #pragma unroll 8
        for (int k = 0; k < 256; ++k) acc = fmaf(Wl2T[k * 256 + tid], sh_z1[k], acc);
        sh_z2[tid] = fmaxf(acc, 0.f);
    }
    __syncthreads();

    {   // out[o] = sum_k z2[k]*Wl3T[k][o] + bl3[o]  (two outputs per thread)
        float a0 = bl3[tid], a1 = bl3[tid + 256];
        #pragma unroll 8
        for (int k = 0; k < 256; ++k) {
            const float z = sh_z2[k];
            a0 = fmaf(Wl3T[k * 512 + tid],       z, a0);
            a1 = fmaf(Wl3T[k * 512 + tid + 256], z, a1);
        }
        out[(size_t)b * 512 + tid]       = a0;
        out[(size_t)b * 512 + 256 + tid] = a1;
    }
}

extern "C" void kernel_launch(void* const* d_in, const int* in_sizes, int n_in,
                              void* d_out, int out_size, void* d_ws, size_t ws_size,
                              hipStream_t stream) {
    const float* x       = (const float*)d_in[0];
    const int*   lengths = (const int*)d_in[1];
    const float* W1      = (const float*)d_in[2];
    const float* b1      = (const float*)d_in[3];
    const float* W2      = (const float*)d_in[4];
    const float* b2      = (const float*)d_in[5];
    const float* Wl1     = (const float*)d_in[6];
    const float* bl1     = (const float*)d_in[7];
    const float* Wl2     = (const float*)d_in[8];
    const float* bl2     = (const float*)d_in[9];
    const float* Wl3     = (const float*)d_in[10];
    const float* bl3     = (const float*)d_in[11];
    float* out = (float*)d_out;

    char* ws = (char*)d_ws;
    float* s_part = (float*)(ws + OFF_SPART);
    short* wb     = (short*)(ws + OFF_WB);
    float* W2T    = (float*)(ws + OFF_W2T);
    float* Wl1T   = (float*)(ws + OFF_WL1T);
    float* Wl2T   = (float*)(ws + OFF_WL2T);
    float* Wl3T   = (float*)(ws + OFF_WL3T);

    prep_kernel<<<dim3((PREP_TOTAL + 255) / 256), dim3(256), 0, stream>>>(
        W1, W2, Wl1, Wl2, Wl3, wb, W2T, Wl1T, Wl2T, Wl3T);
    conv_pool_kernel<<<dim3(NB * NCHUNK), dim3(256), 0, stream>>>(
        x, lengths, wb, b1, s_part);
    mlp_kernel<<<dim3(NB), dim3(256), 0, stream>>>(
        s_part, lengths, W2T, b2, Wl1T, bl1, Wl2T, bl2, Wl3T, bl3, out);
}